// Round 4
// baseline (784.435 us; speedup 1.0000x reference)
//
#include <hip/hip_runtime.h>
#include <math.h>

#define SEQ 2048
#define DMODEL 1024
#define NH 16
#define DK 64
#define BATCH 2

using bf16x8 = __attribute__((ext_vector_type(8))) __bf16;
using bf16x4 = __attribute__((ext_vector_type(4))) __bf16;
using f32x4  = __attribute__((ext_vector_type(4))) float;

__device__ inline f32x4 mfma16(bf16x8 a, bf16x8 b, f32x4 c) {
    return __builtin_amdgcn_mfma_f32_16x16x32_bf16(a, b, c, 0, 0, 0);
}

__device__ inline void load_lds16(const void* g, void* l) {
    __builtin_amdgcn_global_load_lds(
        (const __attribute__((address_space(1))) void*)g,
        (__attribute__((address_space(3))) void*)l, 16, 0, 0);
}

// ---------------------------------------------------------------------------
// fp32 -> bf16 conversion: 3 activations (4096x1024) + 4 weights (1024x1024).
// ---------------------------------------------------------------------------
__global__ __launch_bounds__(256) void conv_bf16(
        const float* __restrict__ q, const float* __restrict__ k,
        const float* __restrict__ v, const float* __restrict__ wq,
        const float* __restrict__ wk, const float* __restrict__ wv,
        const float* __restrict__ wo,
        __bf16* __restrict__ oq, __bf16* __restrict__ ok, __bf16* __restrict__ ov,
        __bf16* __restrict__ owq, __bf16* __restrict__ owk,
        __bf16* __restrict__ owv, __bf16* __restrict__ owo) {
    int bid = blockIdx.x;
    const float* src;
    __bf16* dst;
    size_t off;
    if (bid < 3072) {
        int ti = bid >> 10;
        src = ti == 0 ? q : (ti == 1 ? k : v);
        dst = ti == 0 ? oq : (ti == 1 ? ok : ov);
        off = (size_t)(bid & 1023) * 4096;
    } else {
        int ti = (bid - 3072) >> 8;
        src = ti == 0 ? wq : (ti == 1 ? wk : (ti == 2 ? wv : wo));
        dst = ti == 0 ? owq : (ti == 1 ? owk : (ti == 2 ? owv : owo));
        off = (size_t)((bid - 3072) & 255) * 4096;
    }
    src += off; dst += off;
    const int t = threadIdx.x;
#pragma unroll
    for (int i = 0; i < 4; ++i) {
        float4 x = *(const float4*)(src + t * 4 + i * 1024);
        bf16x4 y;
        y[0] = (__bf16)x.x; y[1] = (__bf16)x.y;
        y[2] = (__bf16)x.z; y[3] = (__bf16)x.w;
        *(bf16x4*)(dst + t * 4 + i * 1024) = y;
    }
}

// ---------------------------------------------------------------------------
// bf16 MFMA GEMM NT (unchanged from R3): C[m,n] = dot(A[m,:], B[n,:]), K=1024.
// mode 0: fp32 out [M][N] ; mode 1: bf16 out [M][N] ; mode 2: bf16 Vt layout.
// ---------------------------------------------------------------------------
__global__ __launch_bounds__(256) void gemm_bf16(const __bf16* __restrict__ A,
                                                 const __bf16* __restrict__ B,
                                                 void* __restrict__ out,
                                                 int mode) {
    __shared__ __align__(16) __bf16 As[8192];
    __shared__ __align__(16) __bf16 Bs[8192];
    const int t    = threadIdx.x;
    const int w    = t >> 6;
    const int lane = t & 63;
    const int m    = lane & 15;
    const int kg   = lane >> 4;
    const int wr   = w >> 1, wc = w & 1;
    const int m0   = blockIdx.y * 128, n0 = blockIdx.x * 128;
    const int N    = gridDim.x * 128;

    f32x4 acc[4][4] = {};

    for (int k0 = 0; k0 < 1024; k0 += 64) {
        __syncthreads();
#pragma unroll
        for (int i = 0; i < 4; ++i) {
            const int blk = w * 4 + i;
            const int mt = blk >> 1, kt = blk & 1;
            const __bf16* ga = A + (size_t)(m0 + mt * 16 + m) * 1024 + k0 + kt * 32 + kg * 8;
            load_lds16(ga, &As[blk * 512]);
            const __bf16* gb = B + (size_t)(n0 + mt * 16 + m) * 1024 + k0 + kt * 32 + kg * 8;
            load_lds16(gb, &Bs[blk * 512]);
        }
        __syncthreads();
#pragma unroll
        for (int kt = 0; kt < 2; ++kt) {
            bf16x8 af[4], bg[4];
#pragma unroll
            for (int i = 0; i < 4; ++i) {
                af[i] = *(const bf16x8*)&As[((wr * 4 + i) * 2 + kt) * 512 + lane * 8];
                bg[i] = *(const bf16x8*)&Bs[((wc * 4 + i) * 2 + kt) * 512 + lane * 8];
            }
#pragma unroll
            for (int i = 0; i < 4; ++i)
#pragma unroll
                for (int j = 0; j < 4; ++j)
                    acc[i][j] = mfma16(af[i], bg[j], acc[i][j]);
        }
    }

#pragma unroll
    for (int i = 0; i < 4; ++i) {
        const int rb = m0 + wr * 64 + i * 16 + kg * 4;
#pragma unroll
        for (int j = 0; j < 4; ++j) {
            const int gc = n0 + wc * 64 + j * 16 + m;
#pragma unroll
            for (int r = 0; r < 4; ++r) {
                const int gr = rb + r;
                const float vv = acc[i][j][r];
                if (mode == 0) {
                    ((float*)out)[(size_t)gr * N + gc] = vv;
                } else if (mode == 1) {
                    ((__bf16*)out)[(size_t)gr * N + gc] = (__bf16)vv;
                } else {
                    const int hh = gr >> 6, dd = gr & 63;
                    const int bb = gc >> 11, ss = gc & 2047;
                    ((__bf16*)out)[(((size_t)bb * NH + hh) * DK + dd) * SEQ + ss] = (__bf16)vv;
                }
            }
        }
    }
}

// ---------------------------------------------------------------------------
// MFMA attention, q-tile 8 / 512 threads / 65.7 KB LDS -> 2 blocks per CU.
// Wave w owns q-row w for softmax/avg, k-range [w*256,(w+1)*256) for PV.
// MFMA A-frags duplicate q rows (m&7); kg>=2 C-rows are discarded dupes.
// ---------------------------------------------------------------------------
__global__ __launch_bounds__(512) void attn_mfma(const __bf16* __restrict__ Qp,
                                                 const __bf16* __restrict__ Kp,
                                                 const __bf16* __restrict__ Vt,
                                                 __bf16* __restrict__ att,
                                                 float* __restrict__ avg) {
    __shared__ float sc[8 * 2052 + 8];
    float* stats = &sc[8 * 2052];

    const int t    = threadIdx.x;
    const int w    = t >> 6;          // wave id == owned q row
    const int lane = t & 63;
    const int q0   = blockIdx.x * 8;
    const int b    = blockIdx.y;

    const int m  = lane & 15;
    const int kg = lane >> 4;
    const int mq = m & 7;             // valid q row (rows 8-15 duplicate 0-7)

    f32x4 avreg[8] = {};              // 8 rows x 2048 / 512 thr = 32 f32

    for (int h = 0; h < NH; ++h) {
        const __bf16* Qh = Qp + ((size_t)b * SEQ + q0) * 1024 + h * 64;
        const __bf16* Kh = Kp + (size_t)b * SEQ * 1024 + h * 64;
        const __bf16* Vh = Vt + ((size_t)b * NH + h) * DK * SEQ;

        bf16x8 a0 = *(const bf16x8*)(Qh + mq * 1024 + kg * 8);
        bf16x8 a1 = *(const bf16x8*)(Qh + mq * 1024 + kg * 8 + 32);

        // ---- scores: sc[q][k] = (Q.K)/8 ; each wave does 16 nt tiles ----
        for (int nt = w; nt < 128; nt += 8) {
            const __bf16* Kt = Kh + (size_t)(nt * 16 + m) * 1024 + kg * 8;
            bf16x8 b0 = *(const bf16x8*)(Kt);
            bf16x8 b1 = *(const bf16x8*)(Kt + 32);
            f32x4 c = {};
            c = mfma16(a0, b0, c);
            c = mfma16(a1, b1, c);
            if (kg < 2) {
#pragma unroll
                for (int r = 0; r < 4; ++r)
                    sc[(kg * 4 + r) * 2052 + nt * 16 + m] = c[r] * 0.125f;
            }
        }
        __syncthreads();

        // ---- softmax on row w (wave-local, 64 lanes) + avg accumulate ----
        {
            float* row = &sc[w * 2052];
            f32x4 ev[8];
            float mx = -1e30f;
#pragma unroll
            for (int j = 0; j < 8; ++j) {
                ev[j] = *(const f32x4*)&row[lane * 4 + j * 256];
                mx = fmaxf(mx, fmaxf(fmaxf(ev[j][0], ev[j][1]), fmaxf(ev[j][2], ev[j][3])));
            }
#pragma unroll
            for (int off = 32; off > 0; off >>= 1) mx = fmaxf(mx, __shfl_xor(mx, off, 64));
            float sum = 0.f;
#pragma unroll
            for (int j = 0; j < 8; ++j) {
                ev[j][0] = __expf(ev[j][0] - mx); ev[j][1] = __expf(ev[j][1] - mx);
                ev[j][2] = __expf(ev[j][2] - mx); ev[j][3] = __expf(ev[j][3] - mx);
                *(f32x4*)&row[lane * 4 + j * 256] = ev[j];
                sum += ev[j][0] + ev[j][1] + ev[j][2] + ev[j][3];
            }
#pragma unroll
            for (int off = 32; off > 0; off >>= 1) sum += __shfl_xor(sum, off, 64);
            const float inv = 1.0f / sum;
            if (lane == 0) stats[w] = inv;
            const float s = inv * (1.0f / NH);
#pragma unroll
            for (int j = 0; j < 8; ++j) avreg[j] += ev[j] * s;
        }
        __syncthreads();   // stats + exp'd rows visible to all waves

        // ---- PV: wave w owns k-range [w*256, w*256+256) ----
        f32x4 pv[4] = {};
        {
            const float invm = stats[mq];
            const int kw = w * 256;
#pragma unroll
            for (int c8 = 0; c8 < 8; ++c8) {
                const int kb = kw + c8 * 32 + kg * 8;
                f32x4 p0 = *(const f32x4*)&sc[mq * 2052 + kb];
                f32x4 p1 = *(const f32x4*)&sc[mq * 2052 + kb + 4];
                bf16x8 af;
                af[0] = (__bf16)(p0[0] * invm); af[1] = (__bf16)(p0[1] * invm);
                af[2] = (__bf16)(p0[2] * invm); af[3] = (__bf16)(p0[3] * invm);
                af[4] = (__bf16)(p1[0] * invm); af[5] = (__bf16)(p1[1] * invm);
                af[6] = (__bf16)(p1[2] * invm); af[7] = (__bf16)(p1[3] * invm);
#pragma unroll
                for (int nt = 0; nt < 4; ++nt) {
                    bf16x8 bv = *(const bf16x8*)(Vh + (size_t)(nt * 16 + m) * SEQ + kb);
                    pv[nt] = mfma16(af, bv, pv[nt]);
                }
            }
        }
        __syncthreads();   // all p reads complete before sc reuse

        // ---- cross-wave reduce of PV partials via sc (first 16 KB, dead) ----
        if (kg < 2) {
#pragma unroll
            for (int nt = 0; nt < 4; ++nt)
#pragma unroll
                for (int r = 0; r < 4; ++r)
                    sc[(w * 8 + kg * 4 + r) * 64 + nt * 16 + m] = pv[nt][r];
        }
        __syncthreads();
        {
            const int q = w, d = lane;
            float s = 0.f;
#pragma unroll
            for (int ww = 0; ww < 8; ++ww) s += sc[(ww * 8 + q) * 64 + d];
            att[((size_t)b * SEQ + q0 + q) * DMODEL + h * DK + d] = (__bf16)s;
        }
        __syncthreads();   // before next head overwrites sc
    }

    // ---- write avg_attention once (wave w -> row q0+w) ----
    {
        float* dst = avg + ((size_t)b * SEQ + q0 + w) * SEQ;
#pragma unroll
        for (int j = 0; j < 8; ++j)
            *(f32x4*)&dst[lane * 4 + j * 256] = avreg[j];
    }
}

// ---------------------------------------------------------------------------
extern "C" void kernel_launch(void* const* d_in, const int* in_sizes, int n_in,
                              void* d_out, int out_size, void* d_ws, size_t ws_size,
                              hipStream_t stream) {
    const float* query = (const float*)d_in[0];
    const float* key   = (const float*)d_in[1];
    const float* value = (const float*)d_in[2];
    const float* w_q   = (const float*)d_in[3];
    const float* w_k   = (const float*)d_in[4];
    const float* w_v   = (const float*)d_in[5];
    const float* w_o   = (const float*)d_in[6];

    float* out = (float*)d_out;
    float* avg = out + (size_t)BATCH * SEQ * DMODEL;

    __bf16* Xq = (__bf16*)d_ws;            // [4096][1024]
    __bf16* Xk = Xq + 4194304;
    __bf16* Xv = Xk + 4194304;
    __bf16* Wq = Xv + 4194304;             // [1024][1024]
    __bf16* Wk = Wq + 1048576;
    __bf16* Wv = Wk + 1048576;
    __bf16* Wo = Wv + 1048576;
    __bf16* Qr = Wo + 1048576;             // [4096][1024] row-major
    __bf16* Kr = Qr + 4194304;
    __bf16* Vt = Kr + 4194304;             // [b][h][dk][s]
    __bf16* At = Xq;                       // reuse: Xq dead after Q projection

    conv_bf16<<<4096, 256, 0, stream>>>(query, key, value, w_q, w_k, w_v, w_o,
                                        Xq, Xk, Xv, Wq, Wk, Wv, Wo);

    gemm_bf16<<<dim3(8, 32), 256, 0, stream>>>(Xq, Wq, Qr, 1);   // Q row-major
    gemm_bf16<<<dim3(8, 32), 256, 0, stream>>>(Xk, Wk, Kr, 1);   // K row-major
    gemm_bf16<<<dim3(32, 8), 256, 0, stream>>>(Wv, Xv, Vt, 2);   // V^T

    attn_mfma<<<dim3(SEQ / 8, BATCH), 512, 0, stream>>>(Qr, Kr, Vt, At, avg);

    gemm_bf16<<<dim3(8, 32), 256, 0, stream>>>(At, Wo, out, 0);  // fp32 out
}

// Round 5
// 543.803 us; speedup vs baseline: 1.4425x; 1.4425x over previous
//
#include <hip/hip_runtime.h>
#include <math.h>

#define SEQ 2048
#define DMODEL 1024
#define NH 16
#define DK 64
#define BATCH 2

using bf16x8 = __attribute__((ext_vector_type(8))) __bf16;
using bf16x4 = __attribute__((ext_vector_type(4))) __bf16;
using f32x4  = __attribute__((ext_vector_type(4))) float;

__device__ inline f32x4 mfma16(bf16x8 a, bf16x8 b, f32x4 c) {
    return __builtin_amdgcn_mfma_f32_16x16x32_bf16(a, b, c, 0, 0, 0);
}

__device__ inline void load_lds16(const void* g, void* l) {
    __builtin_amdgcn_global_load_lds(
        (const __attribute__((address_space(1))) void*)g,
        (__attribute__((address_space(3))) void*)l, 16, 0, 0);
}

// ---------------------------------------------------------------------------
// fp32 -> bf16 conversion: 3 activations (4096x1024) + 4 weights (1024x1024).
// ---------------------------------------------------------------------------
__global__ __launch_bounds__(256) void conv_bf16(
        const float* __restrict__ q, const float* __restrict__ k,
        const float* __restrict__ v, const float* __restrict__ wq,
        const float* __restrict__ wk, const float* __restrict__ wv,
        const float* __restrict__ wo,
        __bf16* __restrict__ oq, __bf16* __restrict__ ok, __bf16* __restrict__ ov,
        __bf16* __restrict__ owq, __bf16* __restrict__ owk,
        __bf16* __restrict__ owv, __bf16* __restrict__ owo) {
    int bid = blockIdx.x;
    const float* src;
    __bf16* dst;
    size_t off;
    if (bid < 3072) {
        int ti = bid >> 10;
        src = ti == 0 ? q : (ti == 1 ? k : v);
        dst = ti == 0 ? oq : (ti == 1 ? ok : ov);
        off = (size_t)(bid & 1023) * 4096;
    } else {
        int ti = (bid - 3072) >> 8;
        src = ti == 0 ? wq : (ti == 1 ? wk : (ti == 2 ? wv : wo));
        dst = ti == 0 ? owq : (ti == 1 ? owk : (ti == 2 ? owv : owo));
        off = (size_t)((bid - 3072) & 255) * 4096;
    }
    src += off; dst += off;
    const int t = threadIdx.x;
#pragma unroll
    for (int i = 0; i < 4; ++i) {
        float4 x = *(const float4*)(src + t * 4 + i * 1024);
        bf16x4 y;
        y[0] = (__bf16)x.x; y[1] = (__bf16)x.y;
        y[2] = (__bf16)x.z; y[3] = (__bf16)x.w;
        *(bf16x4*)(dst + t * 4 + i * 1024) = y;
    }
}

// ---------------------------------------------------------------------------
// bf16 MFMA GEMM NT (unchanged from R3): C[m,n] = dot(A[m,:], B[n,:]), K=1024.
// mode 0: fp32 out [M][N] ; mode 1: bf16 out [M][N] ; mode 2: bf16 Vt layout.
// ---------------------------------------------------------------------------
__global__ __launch_bounds__(256) void gemm_bf16(const __bf16* __restrict__ A,
                                                 const __bf16* __restrict__ B,
                                                 void* __restrict__ out,
                                                 int mode) {
    __shared__ __align__(16) __bf16 As[8192];
    __shared__ __align__(16) __bf16 Bs[8192];
    const int t    = threadIdx.x;
    const int w    = t >> 6;
    const int lane = t & 63;
    const int m    = lane & 15;
    const int kg   = lane >> 4;
    const int wr   = w >> 1, wc = w & 1;
    const int m0   = blockIdx.y * 128, n0 = blockIdx.x * 128;
    const int N    = gridDim.x * 128;

    f32x4 acc[4][4] = {};

    for (int k0 = 0; k0 < 1024; k0 += 64) {
        __syncthreads();
#pragma unroll
        for (int i = 0; i < 4; ++i) {
            const int blk = w * 4 + i;
            const int mt = blk >> 1, kt = blk & 1;
            const __bf16* ga = A + (size_t)(m0 + mt * 16 + m) * 1024 + k0 + kt * 32 + kg * 8;
            load_lds16(ga, &As[blk * 512]);
            const __bf16* gb = B + (size_t)(n0 + mt * 16 + m) * 1024 + k0 + kt * 32 + kg * 8;
            load_lds16(gb, &Bs[blk * 512]);
        }
        __syncthreads();
#pragma unroll
        for (int kt = 0; kt < 2; ++kt) {
            bf16x8 af[4], bg[4];
#pragma unroll
            for (int i = 0; i < 4; ++i) {
                af[i] = *(const bf16x8*)&As[((wr * 4 + i) * 2 + kt) * 512 + lane * 8];
                bg[i] = *(const bf16x8*)&Bs[((wc * 4 + i) * 2 + kt) * 512 + lane * 8];
            }
#pragma unroll
            for (int i = 0; i < 4; ++i)
#pragma unroll
                for (int j = 0; j < 4; ++j)
                    acc[i][j] = mfma16(af[i], bg[j], acc[i][j]);
        }
    }

#pragma unroll
    for (int i = 0; i < 4; ++i) {
        const int rb = m0 + wr * 64 + i * 16 + kg * 4;
#pragma unroll
        for (int j = 0; j < 4; ++j) {
            const int gc = n0 + wc * 64 + j * 16 + m;
#pragma unroll
            for (int r = 0; r < 4; ++r) {
                const int gr = rb + r;
                const float vv = acc[i][j][r];
                if (mode == 0) {
                    ((float*)out)[(size_t)gr * N + gc] = vv;
                } else if (mode == 1) {
                    ((__bf16*)out)[(size_t)gr * N + gc] = (__bf16)vv;
                } else {
                    const int hh = gr >> 6, dd = gr & 63;
                    const int bb = gc >> 11, ss = gc & 2047;
                    ((__bf16*)out)[(((size_t)bb * NH + hh) * DK + dd) * SEQ + ss] = (__bf16)vv;
                }
            }
        }
    }
}

// ---------------------------------------------------------------------------
// MFMA attention: 16 q-rows/block, 1024 threads = 16 waves (4 waves/SIMD).
// No duplicated MFMA rows. Wave w owns q-row w (softmax + avg in registers),
// PV k-range [w*128,(w+1)*128). Scores fp32 in LDS (stride 2052); PV partials
// reduced via stride-68 scratch overlaid on dead score rows.
// ---------------------------------------------------------------------------
__global__ __launch_bounds__(1024) void attn_mfma(const __bf16* __restrict__ Qp,
                                                  const __bf16* __restrict__ Kp,
                                                  const __bf16* __restrict__ Vt,
                                                  __bf16* __restrict__ att,
                                                  float* __restrict__ avg) {
    __shared__ float sc[16 * 2052 + 16];   // 131.4 KB: scores + stats tail
    float* stats = &sc[16 * 2052];

    const int t    = threadIdx.x;
    const int w    = t >> 6;          // wave id (0..15) == owned q row
    const int lane = t & 63;
    const int q0   = blockIdx.x * 16;
    const int b    = blockIdx.y;

    const int m  = lane & 15;
    const int kg = lane >> 4;

    f32x4 avreg[8] = {};              // 2048 cols / 64 lanes = 32 f32 per lane

    for (int h = 0; h < NH; ++h) {
        const __bf16* Qh = Qp + ((size_t)b * SEQ + q0) * 1024 + h * 64;
        const __bf16* Kh = Kp + (size_t)b * SEQ * 1024 + h * 64;
        const __bf16* Vh = Vt + ((size_t)b * NH + h) * DK * SEQ;

        // A-frags: Q[16,64] (all 16 rows real)
        bf16x8 a0 = *(const bf16x8*)(Qh + m * 1024 + kg * 8);
        bf16x8 a1 = *(const bf16x8*)(Qh + m * 1024 + kg * 8 + 32);

        // ---- scores: sc[q][k] = (Q.K)/8 ; each wave does 8 nt tiles ----
        for (int nt = w; nt < 128; nt += 16) {
            const __bf16* Kt = Kh + (size_t)(nt * 16 + m) * 1024 + kg * 8;
            bf16x8 b0 = *(const bf16x8*)(Kt);
            bf16x8 b1 = *(const bf16x8*)(Kt + 32);
            f32x4 c = {};
            c = mfma16(a0, b0, c);
            c = mfma16(a1, b1, c);
#pragma unroll
            for (int r = 0; r < 4; ++r)
                sc[(kg * 4 + r) * 2052 + nt * 16 + m] = c[r] * 0.125f;
        }
        __syncthreads();

        // ---- softmax on row w (64 lanes, 32 elems/lane) + fused avg accum ----
        {
            float* row = &sc[w * 2052];
            f32x4 ev[8];
            float mx = -1e30f;
#pragma unroll
            for (int j = 0; j < 8; ++j) {
                ev[j] = *(const f32x4*)&row[lane * 4 + j * 256];
                mx = fmaxf(mx, fmaxf(fmaxf(ev[j][0], ev[j][1]), fmaxf(ev[j][2], ev[j][3])));
            }
#pragma unroll
            for (int off = 32; off > 0; off >>= 1) mx = fmaxf(mx, __shfl_xor(mx, off, 64));
            float sum = 0.f;
#pragma unroll
            for (int j = 0; j < 8; ++j) {
                ev[j][0] = __expf(ev[j][0] - mx); ev[j][1] = __expf(ev[j][1] - mx);
                ev[j][2] = __expf(ev[j][2] - mx); ev[j][3] = __expf(ev[j][3] - mx);
                *(f32x4*)&row[lane * 4 + j * 256] = ev[j];
                sum += ev[j][0] + ev[j][1] + ev[j][2] + ev[j][3];
            }
#pragma unroll
            for (int off = 32; off > 0; off >>= 1) sum += __shfl_xor(sum, off, 64);
            const float inv = 1.0f / sum;
            if (lane == 0) stats[w] = inv;
            const float s = inv * (1.0f / NH);
#pragma unroll
            for (int j = 0; j < 8; ++j) avreg[j] += ev[j] * s;
        }
        __syncthreads();   // stats + exp'd rows visible to all waves

        // ---- PV: wave w owns k-range [w*128, w*128+128) ----
        f32x4 pv[4] = {};
        {
            const float invm = stats[m];
            const int kw = w * 128;
#pragma unroll
            for (int c8 = 0; c8 < 4; ++c8) {
                const int kb = kw + c8 * 32 + kg * 8;
                f32x4 p0 = *(const f32x4*)&sc[m * 2052 + kb];
                f32x4 p1 = *(const f32x4*)&sc[m * 2052 + kb + 4];
                bf16x8 af;
                af[0] = (__bf16)(p0[0] * invm); af[1] = (__bf16)(p0[1] * invm);
                af[2] = (__bf16)(p0[2] * invm); af[3] = (__bf16)(p0[3] * invm);
                af[4] = (__bf16)(p1[0] * invm); af[5] = (__bf16)(p1[1] * invm);
                af[6] = (__bf16)(p1[2] * invm); af[7] = (__bf16)(p1[3] * invm);
#pragma unroll
                for (int nt = 0; nt < 4; ++nt) {
                    bf16x8 bv = *(const bf16x8*)(Vh + (size_t)(nt * 16 + m) * SEQ + kb);
                    pv[nt] = mfma16(af, bv, pv[nt]);
                }
            }
        }
        __syncthreads();   // all P reads complete before scratch overwrites sc

        // ---- 16-way cross-wave reduce via scratch (stride 68, 2-way banks) ----
#pragma unroll
        for (int nt = 0; nt < 4; ++nt)
#pragma unroll
            for (int r = 0; r < 4; ++r)
                sc[(w * 16 + kg * 4 + r) * 68 + nt * 16 + m] = pv[nt][r];
        __syncthreads();
        {
            const int q = t >> 6, d = t & 63;   // one output per thread
            float s = 0.f;
#pragma unroll
            for (int ww = 0; ww < 16; ++ww) s += sc[(ww * 16 + q) * 68 + d];
            att[((size_t)b * SEQ + q0 + q) * DMODEL + h * DK + d] = (__bf16)s;
        }
        __syncthreads();   // scratch reads done before next head's scores
    }

    // ---- write avg_attention once (wave w -> row q0+w) ----
    {
        float* dst = avg + ((size_t)b * SEQ + q0 + w) * SEQ;
#pragma unroll
        for (int j = 0; j < 8; ++j)
            *(f32x4*)&dst[lane * 4 + j * 256] = avreg[j];
    }
}

// ---------------------------------------------------------------------------
extern "C" void kernel_launch(void* const* d_in, const int* in_sizes, int n_in,
                              void* d_out, int out_size, void* d_ws, size_t ws_size,
                              hipStream_t stream) {
    const float* query = (const float*)d_in[0];
    const float* key   = (const float*)d_in[1];
    const float* value = (const float*)d_in[2];
    const float* w_q   = (const float*)d_in[3];
    const float* w_k   = (const float*)d_in[4];
    const float* w_v   = (const float*)d_in[5];
    const float* w_o   = (const float*)d_in[6];

    float* out = (float*)d_out;
    float* avg = out + (size_t)BATCH * SEQ * DMODEL;

    __bf16* Xq = (__bf16*)d_ws;            // [4096][1024]
    __bf16* Xk = Xq + 4194304;
    __bf16* Xv = Xk + 4194304;
    __bf16* Wq = Xv + 4194304;             // [1024][1024]
    __bf16* Wk = Wq + 1048576;
    __bf16* Wv = Wk + 1048576;
    __bf16* Wo = Wv + 1048576;
    __bf16* Qr = Wo + 1048576;             // [4096][1024] row-major
    __bf16* Kr = Qr + 4194304;
    __bf16* Vt = Kr + 4194304;             // [b][h][dk][s]
    __bf16* At = Xq;                       // reuse: Xq dead after Q projection

    conv_bf16<<<4096, 256, 0, stream>>>(query, key, value, w_q, w_k, w_v, w_o,
                                        Xq, Xk, Xv, Wq, Wk, Wv, Wo);

    gemm_bf16<<<dim3(8, 32), 256, 0, stream>>>(Xq, Wq, Qr, 1);   // Q row-major
    gemm_bf16<<<dim3(8, 32), 256, 0, stream>>>(Xk, Wk, Kr, 1);   // K row-major
    gemm_bf16<<<dim3(32, 8), 256, 0, stream>>>(Wv, Xv, Vt, 2);   // V^T

    attn_mfma<<<dim3(SEQ / 16, BATCH), 1024, 0, stream>>>(Qr, Kr, Vt, At, avg);

    gemm_bf16<<<dim3(8, 32), 256, 0, stream>>>(At, Wo, out, 0);  // fp32 out
}